// Round 9
// baseline (511.730 us; speedup 1.0000x reference)
//
#include <hip/hip_runtime.h>

// ---------- types / helpers ----------
typedef __attribute__((ext_vector_type(4))) float f32x4;
typedef __attribute__((ext_vector_type(8))) __bf16 bf16x8;

__device__ __forceinline__ unsigned short f2b(float f) {
  unsigned int u = __builtin_bit_cast(unsigned int, f);
  u = (u + 0x7fffu + ((u >> 16) & 1u)) >> 16;
  return (unsigned short)u;
}
__device__ __forceinline__ float b2f(unsigned short h) {
  unsigned int u = ((unsigned int)h) << 16;
  return __builtin_bit_cast(float, u);
}
__device__ __forceinline__ void gl_lds16(const void* g, void* l) {
  __builtin_amdgcn_global_load_lds(
      (const __attribute__((address_space(1))) void*)g,
      (__attribute__((address_space(3))) void*)l, 16, 0, 0);
}

// ---------- fp32 -> bf16 cast ----------
__global__ void cast_kernel(const float* __restrict__ src,
                            unsigned short* __restrict__ dst, int n4) {
  int i = blockIdx.x * blockDim.x + threadIdx.x;
  if (i >= n4) return;
  float4 v = ((const float4*)src)[i];
  ushort4 o;
  o.x = f2b(v.x); o.y = f2b(v.y); o.z = f2b(v.z); o.w = f2b(v.w);
  ((ushort4*)dst)[i] = o;
}

__global__ void cast4_kernel(const float* __restrict__ s0, const float* __restrict__ s1,
                             const float* __restrict__ s2, const float* __restrict__ s3,
                             unsigned short* __restrict__ d0, unsigned short* __restrict__ d1,
                             unsigned short* __restrict__ d2, unsigned short* __restrict__ d3,
                             int n4) {
  int i = blockIdx.x * blockDim.x + threadIdx.x;
  if (i >= n4) return;
  const float* src = blockIdx.y == 0 ? s0 : blockIdx.y == 1 ? s1 : blockIdx.y == 2 ? s2 : s3;
  unsigned short* dst = blockIdx.y == 0 ? d0 : blockIdx.y == 1 ? d1 : blockIdx.y == 2 ? d2 : d3;
  float4 v = ((const float4*)src)[i];
  ushort4 o;
  o.x = f2b(v.x); o.y = f2b(v.y); o.z = f2b(v.z); o.w = f2b(v.w);
  ((ushort4*)dst)[i] = o;
}

// ---------- RoPE cos/sin table ----------
__global__ void rope_table_kernel(float2* __restrict__ tab) {
  int idx = blockIdx.x * blockDim.x + threadIdx.x;
  int l = idx >> 6, i = idx & 63;
  // 10000^(-2i/128) = 2^(-(2i/128)*log2(10000))
  float freq = __builtin_amdgcn_exp2f(-(float)(2 * i) * (13.287712379549449f / 128.0f));
  float th = (float)l * freq;
  tab[idx] = make_float2(cosf(th), sinf(th));
}

// ---------- RoPE apply (z=0: q in-place, pre-scaled; z=1: k in-place + fp32 kout) ----------
__global__ void rope_apply_kernel(unsigned short* __restrict__ qb,
                                  unsigned short* __restrict__ kb,
                                  float* __restrict__ kout,
                                  const float2* __restrict__ tab) {
  const float QS = 0.12751743f;  // (1/sqrt(128)) * log2(e)
  int z = blockIdx.y;
  int p = blockIdx.x * blockDim.x + threadIdx.x;
  int i = p & 63;
  int t = p >> 6;
  int h = t & 15; t >>= 4;
  int l = t & 2047;
  int b = t >> 11;
  int base = ((b * 2048 + l) * 2048) + h * 128 + 2 * i;
  unsigned short* buf = z ? kb : qb;
  float x1 = b2f(buf[base]), x2 = b2f(buf[base + 1]);
  float2 cs = tab[l * 64 + i];
  float r1 = x1 * cs.x - x2 * cs.y;
  float r2 = x1 * cs.y + x2 * cs.x;
  if (z == 1) {
    buf[base] = f2b(r1);
    buf[base + 1] = f2b(r2);
    int obase = ((b * 16 + h) * 2048 + l) * 128 + 2 * i;
    kout[obase] = r1; kout[obase + 1] = r2;
  } else {
    buf[base] = f2b(r1 * QS);
    buf[base + 1] = f2b(r2 * QS);
  }
}

// ---------- tiled transpose: vb (B,L,D) head-slice -> vt (B,H,Dh,L), plus vout fp32 ----------
__global__ __launch_bounds__(256) void transpose_v_kernel(const unsigned short* __restrict__ vb,
                                                          unsigned short* __restrict__ vt,
                                                          float* __restrict__ vout) {
  __shared__ unsigned short t[32][33];
  int bz = blockIdx.z;
  int b = bz >> 4, h = bz & 15;
  int l0 = blockIdx.x * 32, d0 = blockIdx.y * 32;
  const unsigned short* src = vb + (size_t)b * 2048 * 2048 + h * 128;
  unsigned short* dst = vt + (size_t)bz * 128 * 2048;
  int tx = threadIdx.x & 31, ty = threadIdx.x >> 5;
#pragma unroll
  for (int i = 0; i < 4; ++i) {
    unsigned short u = src[(size_t)(l0 + ty + 8 * i) * 2048 + d0 + tx];
    t[ty + 8 * i][tx] = u;
    vout[((size_t)bz * 2048 + l0 + ty + 8 * i) * 128 + d0 + tx] = b2f(u);
  }
  __syncthreads();
#pragma unroll
  for (int i = 0; i < 4; ++i)
    dst[(size_t)(d0 + ty + 8 * i) * 2048 + l0 + tx] = t[tx][ty + 8 * i];
}

// ---------- GEMM v4 (round-6 exact): 8-phase, counted vmcnt, swizzled LDS ----------
template <int BM, int NBN, int OUT_F32>
__global__ __launch_bounds__(512, 2) void gemm4(const unsigned short* __restrict__ A,
                                                const unsigned short* __restrict__ W,
                                                void* __restrict__ C) {
  constexpr int K = 2048, NT = 32;
  constexpr int AH = BM / 2;
  constexpr int MF = BM / 64;
  constexpr int AQ = AH / 64;
  __shared__ unsigned short Asm[2][2][AH * 64];
  __shared__ unsigned short Bsm[2][2][128 * 64];

  const int tid = threadIdx.x, lane = tid & 63, wv = tid >> 6;
  const int wr = wv >> 2, wc = wv & 3;
  const int ln = lane & 15, kg = lane >> 4;

  const int cpx = (int)gridDim.x >> 3;
  const int swzb = ((int)blockIdx.x & 7) * cpx + ((int)blockIdx.x >> 3);
  const int bm = swzb / NBN, bn = swzb % NBN;
  const int m0 = bm * BM, n0 = bn * 256;

  const int rr = lane >> 3;
  const int sws = ((lane & 7) ^ (rr & 7)) * 8;
  const unsigned short* pA = A + (size_t)(m0 + wv * 8 * AQ + rr) * K + sws;
  const unsigned short* pB = W + (size_t)(n0 + wv * 16 + rr) * K + sws;

#define STA_(dd, hh, tt)                                                         \
  { _Pragma("unroll") for (int q = 0; q < AQ; ++q)                               \
      gl_lds16(pA + ((size_t)(hh)*AH + q * 8) * K + (size_t)(tt)*64,             \
               &Asm[dd][hh][(wv * 8 * AQ + q * 8) * 64 + lane * 8]); }
#define STB_(dd, hh, tt)                                                         \
  { _Pragma("unroll") for (int q = 0; q < 2; ++q)                                \
      gl_lds16(pB + ((size_t)(hh)*128 + q * 8) * K + (size_t)(tt)*64,            \
               &Bsm[dd][hh][(wv * 16 + q * 8) * 64 + lane * 8]); }

  const int sw0 = (kg ^ (ln & 7)) * 8;
  const int sw1 = ((4 + kg) ^ (ln & 7)) * 8;
  const int rae = (wr * (AH / 2) + ln) * 64;
  const int rbe = (wc * 32 + ln) * 64;

  f32x4 acc[2 * MF][4] = {};
  bf16x8 aA[MF][2], bB[2][2][2];

#define LDA_(dd, mh)                                                              \
  { _Pragma("unroll") for (int mf = 0; mf < MF; ++mf) {                           \
      aA[mf][0] = *(const bf16x8*)&Asm[dd][mh][rae + mf * 1024 + sw0];            \
      aA[mf][1] = *(const bf16x8*)&Asm[dd][mh][rae + mf * 1024 + sw1];            \
    } }
#define LDB_(dd, bh)                                                              \
  { _Pragma("unroll") for (int nf = 0; nf < 2; ++nf) {                            \
      bB[bh][nf][0] = *(const bf16x8*)&Bsm[dd][bh][rbe + nf * 1024 + sw0];        \
      bB[bh][nf][1] = *(const bf16x8*)&Bsm[dd][bh][rbe + nf * 1024 + sw1];        \
    } }

#define QMM(mh, bh)                                                               \
  {                                                                               \
    __builtin_amdgcn_s_setprio(1);                                                \
    _Pragma("unroll") for (int mf = 0; mf < MF; ++mf)                             \
        _Pragma("unroll") for (int nf = 0; nf < 2; ++nf) {                        \
      acc[(mh)*MF + mf][(bh)*2 + nf] = __builtin_amdgcn_mfma_f32_16x16x32_bf16(   \
          aA[mf][0], bB[bh][nf][0], acc[(mh)*MF + mf][(bh)*2 + nf], 0, 0, 0);     \
      acc[(mh)*MF + mf][(bh)*2 + nf] = __builtin_amdgcn_mfma_f32_16x16x32_bf16(   \
          aA[mf][1], bB[bh][nf][1], acc[(mh)*MF + mf][(bh)*2 + nf], 0, 0, 0);     \
    }                                                                             \
    __builtin_amdgcn_s_setprio(0);                                                \
  }

#define BAR   { __builtin_amdgcn_s_barrier(); __builtin_amdgcn_sched_barrier(0); }
#define VWAIT                                                                     \
  { if (BM == 256) { asm volatile("s_waitcnt vmcnt(4)" ::: "memory"); }           \
    else { asm volatile("s_waitcnt vmcnt(3)" ::: "memory"); } }
#define VW0   { asm volatile("s_waitcnt vmcnt(0)" ::: "memory"); }

  // prologue: tile0 complete (dbuf0); tile1 partial (dbuf1: Ah0, Bh1)
  STA_(0, 0, 0); STB_(0, 0, 0); STB_(0, 1, 0); STA_(0, 1, 0);
  STA_(1, 0, 1); STB_(1, 1, 1);
  VWAIT;

  for (int T = 0; T < NT; T += 2) {
    const bool more = (T + 2) < NT;
    // p1: tile T (dbuf0), quadrant (mh0,bh0)
    LDA_(0, 0); LDB_(0, 0);
    STB_(1, 0, T + 1);
    BAR; QMM(0, 0); BAR;
    // p2: (mh0,bh1)
    LDB_(0, 1);
    STA_(1, 1, T + 1);
    BAR; QMM(0, 1); BAR;
    // p3: (mh1,bh1)
    LDA_(0, 1);
    if (more) STA_(0, 0, T + 2);
    BAR; QMM(1, 1); BAR;
    // p4: (mh1,bh0) — no ds loads
    if (more) { STB_(0, 1, T + 2); VWAIT; } else { VW0; }
    BAR; QMM(1, 0); BAR;
    // p5: tile T+1 (dbuf1), (mh0,bh0)
    LDA_(1, 0); LDB_(1, 0);
    if (more) STB_(0, 0, T + 2);
    BAR; QMM(0, 0); BAR;
    // p6: (mh0,bh1)
    LDB_(1, 1);
    if (more) STA_(0, 1, T + 2);
    BAR; QMM(0, 1); BAR;
    // p7: (mh1,bh1)
    LDA_(1, 1);
    if (more) STA_(1, 0, T + 3);
    BAR; QMM(1, 1); BAR;
    // p8: (mh1,bh0)
    if (more) { STB_(1, 1, T + 3); VWAIT; }
    BAR; QMM(1, 0); BAR;
  }

  // epilogue
  const int mat = bn >> 3;
  unsigned short* Cb = (unsigned short*)C;
  float* Cf = (float*)C;
#pragma unroll
  for (int mh = 0; mh < 2; ++mh)
#pragma unroll
    for (int mf = 0; mf < MF; ++mf)
#pragma unroll
      for (int j = 0; j < 4; ++j) {
        int row = m0 + mh * AH + wr * (AH / 2) + mf * 16 + kg * 4 + j;
        size_t rb = (size_t)mat * 8388608 + (size_t)row * 2048 + (size_t)((bn & 7) * 256);
#pragma unroll
        for (int bh = 0; bh < 2; ++bh)
#pragma unroll
          for (int nf = 0; nf < 2; ++nf) {
            int col = bh * 128 + wc * 32 + nf * 16 + ln;
            float v = acc[mh * MF + mf][bh * 2 + nf][j];
            if (OUT_F32) Cf[rb + col] = v;
            else Cb[rb + col] = f2b(v);
          }
      }
#undef STA_
#undef STB_
#undef LDA_
#undef LDB_
#undef QMM
#undef BAR
#undef VWAIT
#undef VW0
}

// ---------- flash attention v4: K staged in LDS, V direct from L2 (vt), 48KB LDS ----------
__global__ __launch_bounds__(256, 3) void attn4_kernel(const unsigned short* __restrict__ Qb,
                                                       const unsigned short* __restrict__ Kb,
                                                       const unsigned short* __restrict__ Vt,
                                                       unsigned short* __restrict__ Ob) {
  __shared__ unsigned short KS[2][8192];  // [64 kv][128 dh] swizzled
  __shared__ unsigned short PS[4][2048];  // per-wave 32x64 swizzled
  const int D = 2048, L = 2048;
  int tid = threadIdx.x, lane = tid & 63, w = tid >> 6;
  int ln = lane & 15, kg = lane >> 4;
  int bid = blockIdx.x;
  int g = bid >> 5, bh = bid & 31;
  int qt = (g < 8) ? (15 - g) : (g - 8);  // co-resident blocks sum to const work
  int b = bh >> 4, h = bh & 15;
  const size_t base = (size_t)b * L * D + h * 128;
  const unsigned short* Kp = Kb + base;
  const unsigned short* Qp = Qb + base;
  unsigned short* Op = Ob + base;
  const unsigned short* Vp = Vt + (size_t)bh * 128 * L;  // [Dh][L]

  int q0 = qt * 128;
  int qw0 = q0 + w * 32;

  bf16x8 aq[2][4];
#pragma unroll
  for (int m = 0; m < 2; ++m)
#pragma unroll
    for (int kc = 0; kc < 4; ++kc)
      aq[m][kc] = *(const bf16x8*)&Qp[(size_t)(qw0 + m * 16 + ln) * D + kc * 32 + kg * 8];

  f32x4 o[2][8] = {};
  float m2[2][4], ls[2][4];
#pragma unroll
  for (int m = 0; m < 2; ++m)
#pragma unroll
    for (int j = 0; j < 4; ++j) { m2[m][j] = -1e30f; ls[m][j] = 0.f; }

  int l16 = lane >> 4;

#define STAGE(T, NB)                                                                   \
  {                                                                                    \
    int kv0_ = (T) << 6;                                                               \
    _Pragma("unroll") for (int i = 0; i < 4; ++i) {                                    \
      int cK = w * 4 + i;                                                              \
      int r = cK * 4 + l16;                                                            \
      int sw = ln ^ (r & 7);                                                           \
      gl_lds16(Kp + (size_t)(kv0_ + r) * D + sw * 8, &KS[NB][cK * 512 + lane * 8]);    \
    }                                                                                  \
  }

  int nt = 2 * qt + 2;
  int mask_t = 2 * qt + (w >> 1);

  STAGE(0, 0);
  __syncthreads();

  for (int t = 0; t < nt; ++t) {
    int cur = t & 1;
    if (t + 1 < nt) STAGE(t + 1, cur ^ 1);

    if (t <= mask_t) {
      int kv0 = t << 6;
      f32x4 s[2][4] = {};
#pragma unroll
      for (int n = 0; n < 4; ++n)
#pragma unroll
        for (int kc = 0; kc < 4; ++kc) {
          bf16x8 bk = *(const bf16x8*)&KS[cur][(n * 16 + ln) * 128 + (((kc << 2) + kg) ^ (ln & 7)) * 8];
          s[0][n] = __builtin_amdgcn_mfma_f32_16x16x32_bf16(aq[0][kc], bk, s[0][n], 0, 0, 0);
          s[1][n] = __builtin_amdgcn_mfma_f32_16x16x32_bf16(aq[1][kc], bk, s[1][n], 0, 0, 0);
        }
      if (t == mask_t) {
#pragma unroll
        for (int m = 0; m < 2; ++m)
#pragma unroll
          for (int n = 0; n < 4; ++n)
#pragma unroll
            for (int j = 0; j < 4; ++j)
              if (kv0 + n * 16 + ln > qw0 + m * 16 + kg * 4 + j) s[m][n][j] = -1e30f;
      }
      float pmax[2][4];
      bool near = true;
#pragma unroll
      for (int m = 0; m < 2; ++m)
#pragma unroll
        for (int j = 0; j < 4; ++j) {
          pmax[m][j] = fmaxf(fmaxf(s[m][0][j], s[m][1][j]), fmaxf(s[m][2][j], s[m][3][j]));
          near = near && (pmax[m][j] <= m2[m][j] + 8.0f);
        }
      if (!__all(near)) {
#pragma unroll
        for (int m = 0; m < 2; ++m)
#pragma unroll
          for (int j = 0; j < 4; ++j) {
            float mx = pmax[m][j];
#pragma unroll
            for (int d = 1; d < 16; d <<= 1) mx = fmaxf(mx, __shfl_xor(mx, d));
            mx = fmaxf(mx, m2[m][j]);
            float al = __builtin_amdgcn_exp2f(m2[m][j] - mx);
            m2[m][j] = mx;
            ls[m][j] *= al;
#pragma unroll
            for (int dt = 0; dt < 8; ++dt) o[m][dt][j] *= al;
          }
      }
#pragma unroll
      for (int m = 0; m < 2; ++m)
#pragma unroll
        for (int j = 0; j < 4; ++j) {
          int row = m * 16 + kg * 4 + j;
          float acc = 0.f;
#pragma unroll
          for (int n = 0; n < 4; ++n) {
            float p = __builtin_amdgcn_exp2f(s[m][n][j] - m2[m][j]);
            acc += p;
            unsigned int u = __builtin_bit_cast(unsigned int, p);
            PS[w][row * 64 + (((n * 2 + (ln >> 3)) ^ (row & 7)) * 8) + (ln & 7)] =
                (unsigned short)(u >> 16);
          }
          ls[m][j] += acc;
        }
      // PV: V read direct from vt (L2-resident)
#pragma unroll
      for (int kst = 0; kst < 2; ++kst) {
        bf16x8 ap0 = *(const bf16x8*)&PS[w][(ln) * 64 + (((kst << 2) + kg) ^ (ln & 7)) * 8];
        bf16x8 ap1 = *(const bf16x8*)&PS[w][(16 + ln) * 64 + (((kst << 2) + kg) ^ (ln & 7)) * 8];
#pragma unroll
        for (int dt = 0; dt < 8; ++dt) {
          bf16x8 bv = *(const bf16x8*)&Vp[(size_t)(dt * 16 + ln) * L + kv0 + kst * 32 + kg * 8];
          o[0][dt] = __builtin_amdgcn_mfma_f32_16x16x32_bf16(ap0, bv, o[0][dt], 0, 0, 0);
          o[1][dt] = __builtin_amdgcn_mfma_f32_16x16x32_bf16(ap1, bv, o[1][dt], 0, 0, 0);
        }
      }
    }
    __syncthreads();
  }
#undef STAGE

#pragma unroll
  for (int m = 0; m < 2; ++m)
#pragma unroll
    for (int j = 0; j < 4; ++j) {
      float tsum = ls[m][j];
#pragma unroll
      for (int d = 1; d < 16; d <<= 1) tsum += __shfl_xor(tsum, d);
      float inv = 1.0f / tsum;
      int row = qw0 + m * 16 + kg * 4 + j;
#pragma unroll
      for (int dt = 0; dt < 8; ++dt)
        Op[(size_t)row * D + dt * 16 + ln] = f2b(o[m][dt][j] * inv);
    }
}

// ---------- launch ----------
extern "C" void kernel_launch(void* const* d_in, const int* in_sizes, int n_in,
                              void* d_out, int out_size, void* d_ws, size_t ws_size,
                              hipStream_t stream) {
  const float* x  = (const float*)d_in[0];
  // d_in[1] = mask (causal; applied analytically)
  const float* Wq = (const float*)d_in[2];
  const float* Wk = (const float*)d_in[3];
  const float* Wv = (const float*)d_in[4];
  const float* Wo = (const float*)d_in[5];

  char* ws = (char*)d_ws;
  unsigned short* xb  = (unsigned short*)(ws + 0);
  unsigned short* wqb = (unsigned short*)(ws + 16777216);  // wq|wk|wv contiguous = [6144][2048]
  unsigned short* wkb = (unsigned short*)(ws + 25165824);
  unsigned short* wvb = (unsigned short*)(ws + 33554432);
  unsigned short* wob = (unsigned short*)(ws + 41943040);
  unsigned short* qb  = (unsigned short*)(ws + 50331648);  // q|k|v contiguous outputs
  unsigned short* kb  = (unsigned short*)(ws + 67108864);
  unsigned short* vb  = (unsigned short*)(ws + 83886080);
  float2* tab         = (float2*)(ws + 100663296);
  unsigned short* vt  = wqb;  // reuse wq+wk region after QKV GEMM
  unsigned short* ob  = xb;

  float* out  = (float*)d_out;
  float* kout = out + 8388608;
  float* vout = out + 16777216;

  cast_kernel<<<8192, 256, 0, stream>>>(x, xb, 2097152);
  cast4_kernel<<<dim3(4096, 4), 256, 0, stream>>>(Wq, Wk, Wv, Wo, wqb, wkb, wvb, wob, 1048576);
  rope_table_kernel<<<512, 256, 0, stream>>>(tab);

  // fused QKV GEMM: BM=256 @ 384 blocks (best measured operating point)
  gemm4<256, 24, 0><<<384, 512, 0, stream>>>(xb, wqb, qb);

  // v transpose for attention + fp32 vout
  transpose_v_kernel<<<dim3(64, 4, 32), 256, 0, stream>>>(vb, vt, vout);

  // RoPE on q (scaled) and k (+ fp32 kout)
  rope_apply_kernel<<<dim3(16384, 2), 256, 0, stream>>>(qb, kb, kout, tab);

  attn4_kernel<<<512, 256, 0, stream>>>(qb, kb, vt, ob);

  // output projection (fp32 out)
  gemm4<128, 8, 1><<<256, 512, 0, stream>>>(ob, wob, out);
}

// Round 10
// 296.424 us; speedup vs baseline: 1.7263x; 1.7263x over previous
//
#include <hip/hip_runtime.h>

// ---------- types / helpers ----------
typedef __attribute__((ext_vector_type(4))) float f32x4;
typedef __attribute__((ext_vector_type(8))) __bf16 bf16x8;

__device__ __forceinline__ unsigned short f2b(float f) {
  unsigned int u = __builtin_bit_cast(unsigned int, f);
  u = (u + 0x7fffu + ((u >> 16) & 1u)) >> 16;
  return (unsigned short)u;
}
__device__ __forceinline__ float b2f(unsigned short h) {
  unsigned int u = ((unsigned int)h) << 16;
  return __builtin_bit_cast(float, u);
}
__device__ __forceinline__ void gl_lds16(const void* g, void* l) {
  __builtin_amdgcn_global_load_lds(
      (const __attribute__((address_space(1))) void*)g,
      (__attribute__((address_space(3))) void*)l, 16, 0, 0);
}

// ---------- fp32 -> bf16 cast ----------
__global__ void cast_kernel(const float* __restrict__ src,
                            unsigned short* __restrict__ dst, int n4) {
  int i = blockIdx.x * blockDim.x + threadIdx.x;
  if (i >= n4) return;
  float4 v = ((const float4*)src)[i];
  ushort4 o;
  o.x = f2b(v.x); o.y = f2b(v.y); o.z = f2b(v.z); o.w = f2b(v.w);
  ((ushort4*)dst)[i] = o;
}

__global__ void cast4_kernel(const float* __restrict__ s0, const float* __restrict__ s1,
                             const float* __restrict__ s2, const float* __restrict__ s3,
                             unsigned short* __restrict__ d0, unsigned short* __restrict__ d1,
                             unsigned short* __restrict__ d2, unsigned short* __restrict__ d3,
                             int n4) {
  int i = blockIdx.x * blockDim.x + threadIdx.x;
  if (i >= n4) return;
  const float* src = blockIdx.y == 0 ? s0 : blockIdx.y == 1 ? s1 : blockIdx.y == 2 ? s2 : s3;
  unsigned short* dst = blockIdx.y == 0 ? d0 : blockIdx.y == 1 ? d1 : blockIdx.y == 2 ? d2 : d3;
  float4 v = ((const float4*)src)[i];
  ushort4 o;
  o.x = f2b(v.x); o.y = f2b(v.y); o.z = f2b(v.z); o.w = f2b(v.w);
  ((ushort4*)dst)[i] = o;
}

// ---------- RoPE cos/sin table ----------
__global__ void rope_table_kernel(float2* __restrict__ tab) {
  int idx = blockIdx.x * blockDim.x + threadIdx.x;
  int l = idx >> 6, i = idx & 63;
  float freq = __builtin_amdgcn_exp2f(-(float)(2 * i) * (13.287712379549449f / 128.0f));
  float th = (float)l * freq;
  tab[idx] = make_float2(cosf(th), sinf(th));
}

// ---------- RoPE apply (z=0: q in-place, pre-scaled; z=1: k in-place + fp32 kout) ----------
__global__ void rope_apply_kernel(unsigned short* __restrict__ qb,
                                  unsigned short* __restrict__ kb,
                                  float* __restrict__ kout,
                                  const float2* __restrict__ tab) {
  const float QS = 0.12751743f;  // (1/sqrt(128)) * log2(e)
  int z = blockIdx.y;
  int p = blockIdx.x * blockDim.x + threadIdx.x;
  int i = p & 63;
  int t = p >> 6;
  int h = t & 15; t >>= 4;
  int l = t & 2047;
  int b = t >> 11;
  int base = ((b * 2048 + l) * 2048) + h * 128 + 2 * i;
  unsigned short* buf = z ? kb : qb;
  float x1 = b2f(buf[base]), x2 = b2f(buf[base + 1]);
  float2 cs = tab[l * 64 + i];
  float r1 = x1 * cs.x - x2 * cs.y;
  float r2 = x1 * cs.y + x2 * cs.x;
  if (z == 1) {
    buf[base] = f2b(r1);
    buf[base + 1] = f2b(r2);
    int obase = ((b * 16 + h) * 2048 + l) * 128 + 2 * i;
    kout[obase] = r1; kout[obase + 1] = r2;
  } else {
    buf[base] = f2b(r1 * QS);
    buf[base + 1] = f2b(r2 * QS);
  }
}

// ---------- tiled transpose: vb (B,L,D) head-slice -> vt (B,H,Dh,L), plus vout fp32 ----------
__global__ __launch_bounds__(256) void transpose_v_kernel(const unsigned short* __restrict__ vb,
                                                          unsigned short* __restrict__ vt,
                                                          float* __restrict__ vout) {
  __shared__ unsigned short t[32][33];
  int bz = blockIdx.z;
  int b = bz >> 4, h = bz & 15;
  int l0 = blockIdx.x * 32, d0 = blockIdx.y * 32;
  const unsigned short* src = vb + (size_t)b * 2048 * 2048 + h * 128;
  unsigned short* dst = vt + (size_t)bz * 128 * 2048;
  int tx = threadIdx.x & 31, ty = threadIdx.x >> 5;
#pragma unroll
  for (int i = 0; i < 4; ++i) {
    unsigned short u = src[(size_t)(l0 + ty + 8 * i) * 2048 + d0 + tx];
    t[ty + 8 * i][tx] = u;
    vout[((size_t)bz * 2048 + l0 + ty + 8 * i) * 128 + d0 + tx] = b2f(u);
  }
  __syncthreads();
#pragma unroll
  for (int i = 0; i < 4; ++i)
    dst[(size_t)(d0 + ty + 8 * i) * 2048 + l0 + tx] = t[tx][ty + 8 * i];
}

// ---------- GEMM v4 (round-6 exact): 8-phase, counted vmcnt, swizzled LDS ----------
template <int BM, int NBN, int OUT_F32>
__global__ __launch_bounds__(512, 2) void gemm4(const unsigned short* __restrict__ A,
                                                const unsigned short* __restrict__ W,
                                                void* __restrict__ C) {
  constexpr int K = 2048, NT = 32;
  constexpr int AH = BM / 2;
  constexpr int MF = BM / 64;
  constexpr int AQ = AH / 64;
  __shared__ unsigned short Asm[2][2][AH * 64];
  __shared__ unsigned short Bsm[2][2][128 * 64];

  const int tid = threadIdx.x, lane = tid & 63, wv = tid >> 6;
  const int wr = wv >> 2, wc = wv & 3;
  const int ln = lane & 15, kg = lane >> 4;

  const int cpx = (int)gridDim.x >> 3;
  const int swzb = ((int)blockIdx.x & 7) * cpx + ((int)blockIdx.x >> 3);
  const int bm = swzb / NBN, bn = swzb % NBN;
  const int m0 = bm * BM, n0 = bn * 256;

  const int rr = lane >> 3;
  const int sws = ((lane & 7) ^ (rr & 7)) * 8;
  const unsigned short* pA = A + (size_t)(m0 + wv * 8 * AQ + rr) * K + sws;
  const unsigned short* pB = W + (size_t)(n0 + wv * 16 + rr) * K + sws;

#define STA_(dd, hh, tt)                                                         \
  { _Pragma("unroll") for (int q = 0; q < AQ; ++q)                               \
      gl_lds16(pA + ((size_t)(hh)*AH + q * 8) * K + (size_t)(tt)*64,             \
               &Asm[dd][hh][(wv * 8 * AQ + q * 8) * 64 + lane * 8]); }
#define STB_(dd, hh, tt)                                                         \
  { _Pragma("unroll") for (int q = 0; q < 2; ++q)                                \
      gl_lds16(pB + ((size_t)(hh)*128 + q * 8) * K + (size_t)(tt)*64,            \
               &Bsm[dd][hh][(wv * 16 + q * 8) * 64 + lane * 8]); }

  const int sw0 = (kg ^ (ln & 7)) * 8;
  const int sw1 = ((4 + kg) ^ (ln & 7)) * 8;
  const int rae = (wr * (AH / 2) + ln) * 64;
  const int rbe = (wc * 32 + ln) * 64;

  f32x4 acc[2 * MF][4] = {};
  bf16x8 aA[MF][2], bB[2][2][2];

#define LDA_(dd, mh)                                                              \
  { _Pragma("unroll") for (int mf = 0; mf < MF; ++mf) {                           \
      aA[mf][0] = *(const bf16x8*)&Asm[dd][mh][rae + mf * 1024 + sw0];            \
      aA[mf][1] = *(const bf16x8*)&Asm[dd][mh][rae + mf * 1024 + sw1];            \
    } }
#define LDB_(dd, bh)                                                              \
  { _Pragma("unroll") for (int nf = 0; nf < 2; ++nf) {                            \
      bB[bh][nf][0] = *(const bf16x8*)&Bsm[dd][bh][rbe + nf * 1024 + sw0];        \
      bB[bh][nf][1] = *(const bf16x8*)&Bsm[dd][bh][rbe + nf * 1024 + sw1];        \
    } }

#define QMM(mh, bh)                                                               \
  {                                                                               \
    __builtin_amdgcn_s_setprio(1);                                                \
    _Pragma("unroll") for (int mf = 0; mf < MF; ++mf)                             \
        _Pragma("unroll") for (int nf = 0; nf < 2; ++nf) {                        \
      acc[(mh)*MF + mf][(bh)*2 + nf] = __builtin_amdgcn_mfma_f32_16x16x32_bf16(   \
          aA[mf][0], bB[bh][nf][0], acc[(mh)*MF + mf][(bh)*2 + nf], 0, 0, 0);     \
      acc[(mh)*MF + mf][(bh)*2 + nf] = __builtin_amdgcn_mfma_f32_16x16x32_bf16(   \
          aA[mf][1], bB[bh][nf][1], acc[(mh)*MF + mf][(bh)*2 + nf], 0, 0, 0);     \
    }                                                                             \
    __builtin_amdgcn_s_setprio(0);                                                \
  }

#define BAR   { __builtin_amdgcn_s_barrier(); __builtin_amdgcn_sched_barrier(0); }
#define VWAIT                                                                     \
  { if (BM == 256) { asm volatile("s_waitcnt vmcnt(4)" ::: "memory"); }           \
    else { asm volatile("s_waitcnt vmcnt(3)" ::: "memory"); } }
#define VW0   { asm volatile("s_waitcnt vmcnt(0)" ::: "memory"); }

  // prologue: tile0 complete (dbuf0); tile1 partial (dbuf1: Ah0, Bh1)
  STA_(0, 0, 0); STB_(0, 0, 0); STB_(0, 1, 0); STA_(0, 1, 0);
  STA_(1, 0, 1); STB_(1, 1, 1);
  VWAIT;

  for (int T = 0; T < NT; T += 2) {
    const bool more = (T + 2) < NT;
    LDA_(0, 0); LDB_(0, 0);
    STB_(1, 0, T + 1);
    BAR; QMM(0, 0); BAR;
    LDB_(0, 1);
    STA_(1, 1, T + 1);
    BAR; QMM(0, 1); BAR;
    LDA_(0, 1);
    if (more) STA_(0, 0, T + 2);
    BAR; QMM(1, 1); BAR;
    if (more) { STB_(0, 1, T + 2); VWAIT; } else { VW0; }
    BAR; QMM(1, 0); BAR;
    LDA_(1, 0); LDB_(1, 0);
    if (more) STB_(0, 0, T + 2);
    BAR; QMM(0, 0); BAR;
    LDB_(1, 1);
    if (more) STA_(0, 1, T + 2);
    BAR; QMM(0, 1); BAR;
    LDA_(1, 1);
    if (more) STA_(1, 0, T + 3);
    BAR; QMM(1, 1); BAR;
    if (more) { STB_(1, 1, T + 3); VWAIT; }
    BAR; QMM(1, 0); BAR;
  }

  // epilogue
  const int mat = bn >> 3;
  unsigned short* Cb = (unsigned short*)C;
  float* Cf = (float*)C;
#pragma unroll
  for (int mh = 0; mh < 2; ++mh)
#pragma unroll
    for (int mf = 0; mf < MF; ++mf)
#pragma unroll
      for (int j = 0; j < 4; ++j) {
        int row = m0 + mh * AH + wr * (AH / 2) + mf * 16 + kg * 4 + j;
        size_t rb = (size_t)mat * 8388608 + (size_t)row * 2048 + (size_t)((bn & 7) * 256);
#pragma unroll
        for (int bh = 0; bh < 2; ++bh)
#pragma unroll
          for (int nf = 0; nf < 2; ++nf) {
            int col = bh * 128 + wc * 32 + nf * 16 + ln;
            float v = acc[mh * MF + mf][bh * 2 + nf][j];
            if (OUT_F32) Cf[rb + col] = v;
            else Cb[rb + col] = f2b(v);
          }
      }
#undef STA_
#undef STB_
#undef LDA_
#undef LDB_
#undef QMM
#undef BAR
#undef VWAIT
#undef VW0
}

// ---------- flash attention v5: K double-buffered, V single-buffered (64KB LDS, 2 blk/CU) ----------
__global__ __launch_bounds__(256, 2) void attn5_kernel(const unsigned short* __restrict__ Qb,
                                                       const unsigned short* __restrict__ Kb,
                                                       const unsigned short* __restrict__ Vt,
                                                       unsigned short* __restrict__ Ob) {
  __shared__ unsigned short KS[2][8192];  // [64 kv][128 dh] swizzled
  __shared__ unsigned short VS[8192];     // [128 dh][64 kv] swizzled, single buffer
  __shared__ unsigned short PS[4][2048];  // per-wave 32x64 swizzled
  const int D = 2048, L = 2048;
  int tid = threadIdx.x, lane = tid & 63, w = tid >> 6;
  int ln = lane & 15, kg = lane >> 4;
  int bid = blockIdx.x;
  int g = bid >> 5, bh = bid & 31;
  int qt = (g < 8) ? (15 - g) : (g - 8);
  int b = bh >> 4, h = bh & 15;
  const size_t base = (size_t)b * L * D + h * 128;
  const unsigned short* Kp = Kb + base;
  const unsigned short* Qp = Qb + base;
  unsigned short* Op = Ob + base;
  const unsigned short* Vp = Vt + (size_t)bh * 128 * L;

  int q0 = qt * 128;
  int qw0 = q0 + w * 32;

  bf16x8 aq[2][4];
#pragma unroll
  for (int m = 0; m < 2; ++m)
#pragma unroll
    for (int kc = 0; kc < 4; ++kc)
      aq[m][kc] = *(const bf16x8*)&Qp[(size_t)(qw0 + m * 16 + ln) * D + kc * 32 + kg * 8];

  f32x4 o[2][8] = {};
  float m2[2][4], ls[2][4];
#pragma unroll
  for (int m = 0; m < 2; ++m)
#pragma unroll
    for (int j = 0; j < 4; ++j) { m2[m][j] = -1e30f; ls[m][j] = 0.f; }

  int l16 = lane >> 4, l8 = lane >> 3, l7 = lane & 7;

  // V(t) staged at iter-t start (single buffer); consumed by PV(t) after counted-vmcnt + barrier.
#define STAGE_K(T, NB)                                                                 \
  { int kv0_ = (T) << 6;                                                               \
    _Pragma("unroll") for (int i = 0; i < 4; ++i) {                                    \
      int cK = w * 4 + i;                                                              \
      int r = cK * 4 + l16;                                                            \
      int sw = ln ^ (r & 7);                                                           \
      gl_lds16(Kp + (size_t)(kv0_ + r) * D + sw * 8, &KS[NB][cK * 512 + lane * 8]); } }
#define STAGE_V(T)                                                                     \
  { int kv0_ = (T) << 6;                                                               \
    _Pragma("unroll") for (int i = 0; i < 4; ++i) {                                    \
      int cK = w * 4 + i;                                                              \
      int dh = cK * 8 + l8;                                                            \
      int sv = l7 ^ (dh & 7);                                                          \
      gl_lds16(Vp + (size_t)dh * L + kv0_ + sv * 8, &VS[cK * 512 + lane * 8]); } }

  int nt = 2 * qt + 2;
  int mask_t = 2 * qt + (w >> 1);

  STAGE_K(0, 0);
  __syncthreads();  // K(0) published (drains vmcnt)

  for (int t = 0; t < nt; ++t) {
    int cur = t & 1;
    // vmcnt == 0 here (end-of-iter __syncthreads drained). Issue V(t) first, then K(t+1).
    STAGE_V(t);
    bool morek = (t + 1) < nt;
    if (morek) STAGE_K(t + 1, cur ^ 1);

    if (t <= mask_t) {
      int kv0 = t << 6;
      f32x4 s[2][4] = {};
#pragma unroll
      for (int n = 0; n < 4; ++n)
#pragma unroll
        for (int kc = 0; kc < 4; ++kc) {
          bf16x8 bk = *(const bf16x8*)&KS[cur][(n * 16 + ln) * 128 + (((kc << 2) + kg) ^ (ln & 7)) * 8];
          s[0][n] = __builtin_amdgcn_mfma_f32_16x16x32_bf16(aq[0][kc], bk, s[0][n], 0, 0, 0);
          s[1][n] = __builtin_amdgcn_mfma_f32_16x16x32_bf16(aq[1][kc], bk, s[1][n], 0, 0, 0);
        }
      if (t == mask_t) {
#pragma unroll
        for (int m = 0; m < 2; ++m)
#pragma unroll
          for (int n = 0; n < 4; ++n)
#pragma unroll
            for (int j = 0; j < 4; ++j)
              if (kv0 + n * 16 + ln > qw0 + m * 16 + kg * 4 + j) s[m][n][j] = -1e30f;
      }
      float pmax[2][4];
      bool near = true;
#pragma unroll
      for (int m = 0; m < 2; ++m)
#pragma unroll
        for (int j = 0; j < 4; ++j) {
          pmax[m][j] = fmaxf(fmaxf(s[m][0][j], s[m][1][j]), fmaxf(s[m][2][j], s[m][3][j]));
          near = near && (pmax[m][j] <= m2[m][j] + 8.0f);
        }
      if (!__all(near)) {
#pragma unroll
        for (int m = 0; m < 2; ++m)
#pragma unroll
          for (int j = 0; j < 4; ++j) {
            float mx = pmax[m][j];
#pragma unroll
            for (int d = 1; d < 16; d <<= 1) mx = fmaxf(mx, __shfl_xor(mx, d));
            mx = fmaxf(mx, m2[m][j]);
            float al = __builtin_amdgcn_exp2f(m2[m][j] - mx);
            m2[m][j] = mx;
            ls[m][j] *= al;
#pragma unroll
            for (int dt = 0; dt < 8; ++dt) o[m][dt][j] *= al;
          }
      }
#pragma unroll
      for (int m = 0; m < 2; ++m)
#pragma unroll
        for (int j = 0; j < 4; ++j) {
          int row = m * 16 + kg * 4 + j;
          float acc = 0.f;
#pragma unroll
          for (int n = 0; n < 4; ++n) {
            float p = __builtin_amdgcn_exp2f(s[m][n][j] - m2[m][j]);
            acc += p;
            unsigned int u = __builtin_bit_cast(unsigned int, p);
            PS[w][row * 64 + (((n * 2 + (ln >> 3)) ^ (row & 7)) * 8) + (ln & 7)] =
                (unsigned short)(u >> 16);
          }
          ls[m][j] += acc;
        }
    }

    // publish V(t): retire the 4 V loads (K(t+1) loads may stay in flight), then barrier
    if (morek) { asm volatile("s_waitcnt vmcnt(4)" ::: "memory"); }
    else       { asm volatile("s_waitcnt vmcnt(0)" ::: "memory"); }
    __builtin_amdgcn_s_barrier();
    __builtin_amdgcn_sched_barrier(0);

    if (t <= mask_t) {
      int kv0 = t << 6;
      (void)kv0;
#pragma unroll
      for (int kst = 0; kst < 2; ++kst) {
        bf16x8 ap0 = *(const bf16x8*)&PS[w][(ln) * 64 + (((kst << 2) + kg) ^ (ln & 7)) * 8];
        bf16x8 ap1 = *(const bf16x8*)&PS[w][(16 + ln) * 64 + (((kst << 2) + kg) ^ (ln & 7)) * 8];
#pragma unroll
        for (int dt = 0; dt < 8; ++dt) {
          bf16x8 bv = *(const bf16x8*)&VS[(dt * 16 + ln) * 64 + (((kst << 2) + kg) ^ (ln & 7)) * 8];
          o[0][dt] = __builtin_amdgcn_mfma_f32_16x16x32_bf16(ap0, bv, o[0][dt], 0, 0, 0);
          o[1][dt] = __builtin_amdgcn_mfma_f32_16x16x32_bf16(ap1, bv, o[1][dt], 0, 0, 0);
        }
      }
    }
    __syncthreads();  // VS WAR fence + K(t+1) publish (drains vmcnt)
  }
#undef STAGE_K
#undef STAGE_V

#pragma unroll
  for (int m = 0; m < 2; ++m)
#pragma unroll
    for (int j = 0; j < 4; ++j) {
      float tsum = ls[m][j];
#pragma unroll
      for (int d = 1; d < 16; d <<= 1) tsum += __shfl_xor(tsum, d);
      float inv = 1.0f / tsum;
      int row = qw0 + m * 16 + kg * 4 + j;
#pragma unroll
      for (int dt = 0; dt < 8; ++dt)
        Op[(size_t)row * D + dt * 16 + ln] = f2b(o[m][dt][j] * inv);
    }
}

// ---------- launch ----------
extern "C" void kernel_launch(void* const* d_in, const int* in_sizes, int n_in,
                              void* d_out, int out_size, void* d_ws, size_t ws_size,
                              hipStream_t stream) {
  const float* x  = (const float*)d_in[0];
  // d_in[1] = mask (causal; applied analytically)
  const float* Wq = (const float*)d_in[2];
  const float* Wk = (const float*)d_in[3];
  const float* Wv = (const float*)d_in[4];
  const float* Wo = (const float*)d_in[5];

  char* ws = (char*)d_ws;
  unsigned short* xb  = (unsigned short*)(ws + 0);
  unsigned short* wqb = (unsigned short*)(ws + 16777216);  // wq|wk|wv contiguous = [6144][2048]
  unsigned short* wkb = (unsigned short*)(ws + 25165824);
  unsigned short* wvb = (unsigned short*)(ws + 33554432);
  unsigned short* wob = (unsigned short*)(ws + 41943040);
  unsigned short* qb  = (unsigned short*)(ws + 50331648);  // q|k|v contiguous outputs
  unsigned short* kb  = (unsigned short*)(ws + 67108864);
  unsigned short* vb  = (unsigned short*)(ws + 83886080);
  float2* tab         = (float2*)(ws + 100663296);
  unsigned short* vt  = wqb;  // reuse wq+wk region after QKV GEMM
  unsigned short* ob  = xb;

  float* out  = (float*)d_out;
  float* kout = out + 8388608;
  float* vout = out + 16777216;

  cast_kernel<<<8192, 256, 0, stream>>>(x, xb, 2097152);
  cast4_kernel<<<dim3(4096, 4), 256, 0, stream>>>(Wq, Wk, Wv, Wo, wqb, wkb, wvb, wob, 1048576);
  rope_table_kernel<<<512, 256, 0, stream>>>(tab);

  // fused QKV GEMM: BM=256 @ 384 blocks (best measured operating point)
  gemm4<256, 24, 0><<<384, 512, 0, stream>>>(xb, wqb, qb);

  // v transpose for attention + fp32 vout
  transpose_v_kernel<<<dim3(64, 4, 32), 256, 0, stream>>>(vb, vt, vout);

  // RoPE on q (scaled) and k (+ fp32 kout)
  rope_apply_kernel<<<dim3(16384, 2), 256, 0, stream>>>(qb, kb, kout, tab);

  attn5_kernel<<<512, 256, 0, stream>>>(qb, kb, vt, ob);

  // output projection (fp32 out)
  gemm4<128, 8, 1><<<256, 512, 0, stream>>>(ob, wob, out);
}

// Round 12
// 294.661 us; speedup vs baseline: 1.7367x; 1.0060x over previous
//
#include <hip/hip_runtime.h>

// ---------- types / helpers ----------
typedef __attribute__((ext_vector_type(4))) float f32x4;
typedef __attribute__((ext_vector_type(8))) __bf16 bf16x8;

__device__ __forceinline__ unsigned short f2b(float f) {
  unsigned int u = __builtin_bit_cast(unsigned int, f);
  u = (u + 0x7fffu + ((u >> 16) & 1u)) >> 16;
  return (unsigned short)u;
}
__device__ __forceinline__ float b2f(unsigned short h) {
  unsigned int u = ((unsigned int)h) << 16;
  return __builtin_bit_cast(float, u);
}
__device__ __forceinline__ void gl_lds16(const void* g, void* l) {
  __builtin_amdgcn_global_load_lds(
      (const __attribute__((address_space(1))) void*)g,
      (__attribute__((address_space(3))) void*)l, 16, 0, 0);
}

// ---------- prep: cast x (plane 0), cast 4 weights (planes 1-4), rope table (plane 5) ----------
__global__ void prep_kernel(const float* __restrict__ x, unsigned short* __restrict__ xb,
                            const float* __restrict__ s0, const float* __restrict__ s1,
                            const float* __restrict__ s2, const float* __restrict__ s3,
                            unsigned short* __restrict__ d0, unsigned short* __restrict__ d1,
                            unsigned short* __restrict__ d2, unsigned short* __restrict__ d3,
                            float2* __restrict__ tab) {
  int z = blockIdx.y;
  int i = blockIdx.x * blockDim.x + threadIdx.x;
  if (z == 5) {
    if (i >= 131072) return;
    int l = i >> 6, k = i & 63;
    float freq = __builtin_amdgcn_exp2f(-(float)(2 * k) * (13.287712379549449f / 128.0f));
    float th = (float)l * freq;
    tab[i] = make_float2(cosf(th), sinf(th));
    return;
  }
  const float* src; unsigned short* dst; int n4;
  if (z == 0)      { src = x;  dst = xb; n4 = 2097152; }
  else if (z == 1) { src = s0; dst = d0; n4 = 1048576; }
  else if (z == 2) { src = s1; dst = d1; n4 = 1048576; }
  else if (z == 3) { src = s2; dst = d2; n4 = 1048576; }
  else             { src = s3; dst = d3; n4 = 1048576; }
  if (i >= n4) return;
  float4 v = ((const float4*)src)[i];
  ushort4 o;
  o.x = f2b(v.x); o.y = f2b(v.y); o.z = f2b(v.z); o.w = f2b(v.w);
  ((ushort4*)dst)[i] = o;
}

// ---------- fix: y=0 q-rope (in-place, scaled); y=1 k-rope (in-place + fp32 kout);
// ----------      y=2 (first 8192 blocks) v transpose -> vt + fp32 vout
__global__ __launch_bounds__(256) void fix_kernel(unsigned short* __restrict__ qb,
                                                  unsigned short* __restrict__ kb,
                                                  float* __restrict__ kout,
                                                  const unsigned short* __restrict__ vb,
                                                  unsigned short* __restrict__ vt,
                                                  float* __restrict__ vout,
                                                  const float2* __restrict__ tab) {
  __shared__ unsigned short t[32][33];
  const float QS = 0.12751743f;  // (1/sqrt(128)) * log2(e)
  int z = blockIdx.y;
  if (z == 2) {
    int bid = blockIdx.x;
    if (bid >= 8192) return;
    int lx = bid & 63, dy = (bid >> 6) & 3, bz = bid >> 8;
    int b = bz >> 4, h = bz & 15;
    int l0 = lx * 32, d0 = dy * 32;
    const unsigned short* src = vb + (size_t)b * 2048 * 2048 + h * 128;
    unsigned short* dst = vt + (size_t)bz * 128 * 2048;
    int tx = threadIdx.x & 31, ty = threadIdx.x >> 5;
#pragma unroll
    for (int i = 0; i < 4; ++i) {
      unsigned short u = src[(size_t)(l0 + ty + 8 * i) * 2048 + d0 + tx];
      t[ty + 8 * i][tx] = u;
      vout[((size_t)bz * 2048 + l0 + ty + 8 * i) * 128 + d0 + tx] = b2f(u);
    }
    __syncthreads();
#pragma unroll
    for (int i = 0; i < 4; ++i)
      dst[(size_t)(d0 + ty + 8 * i) * 2048 + l0 + tx] = t[tx][ty + 8 * i];
    return;
  }
  // rope planes (identical math to round-10 rope_apply)
  int p = blockIdx.x * blockDim.x + threadIdx.x;
  int i = p & 63;
  int tt = p >> 6;
  int h = tt & 15; tt >>= 4;
  int l = tt & 2047;
  int b = tt >> 11;
  int base = ((b * 2048 + l) * 2048) + h * 128 + 2 * i;
  unsigned short* buf = z ? kb : qb;
  float x1 = b2f(buf[base]), x2 = b2f(buf[base + 1]);
  float2 cs = tab[l * 64 + i];
  float r1 = x1 * cs.x - x2 * cs.y;
  float r2 = x1 * cs.y + x2 * cs.x;
  if (z == 1) {
    buf[base] = f2b(r1);
    buf[base + 1] = f2b(r2);
    int obase = ((b * 16 + h) * 2048 + l) * 128 + 2 * i;
    kout[obase] = r1; kout[obase + 1] = r2;
  } else {
    buf[base] = f2b(r1 * QS);
    buf[base + 1] = f2b(r2 * QS);
  }
}

// ---------- GEMM v4 (round-6/10 exact, frozen): 8-phase, counted vmcnt, swizzled LDS ----------
template <int BM, int NBN, int OUT_F32>
__global__ __launch_bounds__(512, 2) void gemm4(const unsigned short* __restrict__ A,
                                                const unsigned short* __restrict__ W,
                                                void* __restrict__ C) {
  constexpr int K = 2048, NT = 32;
  constexpr int AH = BM / 2;
  constexpr int MF = BM / 64;
  constexpr int AQ = AH / 64;
  __shared__ unsigned short Asm[2][2][AH * 64];
  __shared__ unsigned short Bsm[2][2][128 * 64];

  const int tid = threadIdx.x, lane = tid & 63, wv = tid >> 6;
  const int wr = wv >> 2, wc = wv & 3;
  const int ln = lane & 15, kg = lane >> 4;

  const int cpx = (int)gridDim.x >> 3;
  const int swzb = ((int)blockIdx.x & 7) * cpx + ((int)blockIdx.x >> 3);
  const int bm = swzb / NBN, bn = swzb % NBN;
  const int m0 = bm * BM, n0 = bn * 256;

  const int rr = lane >> 3;
  const int sws = ((lane & 7) ^ (rr & 7)) * 8;
  const unsigned short* pA = A + (size_t)(m0 + wv * 8 * AQ + rr) * K + sws;
  const unsigned short* pB = W + (size_t)(n0 + wv * 16 + rr) * K + sws;

#define STA_(dd, hh, tt)                                                         \
  { _Pragma("unroll") for (int q = 0; q < AQ; ++q)                               \
      gl_lds16(pA + ((size_t)(hh)*AH + q * 8) * K + (size_t)(tt)*64,             \
               &Asm[dd][hh][(wv * 8 * AQ + q * 8) * 64 + lane * 8]); }
#define STB_(dd, hh, tt)                                                         \
  { _Pragma("unroll") for (int q = 0; q < 2; ++q)                                \
      gl_lds16(pB + ((size_t)(hh)*128 + q * 8) * K + (size_t)(tt)*64,            \
               &Bsm[dd][hh][(wv * 16 + q * 8) * 64 + lane * 8]); }

  const int sw0 = (kg ^ (ln & 7)) * 8;
  const int sw1 = ((4 + kg) ^ (ln & 7)) * 8;
  const int rae = (wr * (AH / 2) + ln) * 64;
  const int rbe = (wc * 32 + ln) * 64;

  f32x4 acc[2 * MF][4] = {};
  bf16x8 aA[MF][2], bB[2][2][2];

#define LDA_(dd, mh)                                                              \
  { _Pragma("unroll") for (int mf = 0; mf < MF; ++mf) {                           \
      aA[mf][0] = *(const bf16x8*)&Asm[dd][mh][rae + mf * 1024 + sw0];            \
      aA[mf][1] = *(const bf16x8*)&Asm[dd][mh][rae + mf * 1024 + sw1];            \
    } }
#define LDB_(dd, bh)                                                              \
  { _Pragma("unroll") for (int nf = 0; nf < 2; ++nf) {                            \
      bB[bh][nf][0] = *(const bf16x8*)&Bsm[dd][bh][rbe + nf * 1024 + sw0];        \
      bB[bh][nf][1] = *(const bf16x8*)&Bsm[dd][bh][rbe + nf * 1024 + sw1];        \
    } }

#define QMM(mh, bh)                                                               \
  {                                                                               \
    __builtin_amdgcn_s_setprio(1);                                                \
    _Pragma("unroll") for (int mf = 0; mf < MF; ++mf)                             \
        _Pragma("unroll") for (int nf = 0; nf < 2; ++nf) {                        \
      acc[(mh)*MF + mf][(bh)*2 + nf] = __builtin_amdgcn_mfma_f32_16x16x32_bf16(   \
          aA[mf][0], bB[bh][nf][0], acc[(mh)*MF + mf][(bh)*2 + nf], 0, 0, 0);     \
      acc[(mh)*MF + mf][(bh)*2 + nf] = __builtin_amdgcn_mfma_f32_16x16x32_bf16(   \
          aA[mf][1], bB[bh][nf][1], acc[(mh)*MF + mf][(bh)*2 + nf], 0, 0, 0);     \
    }                                                                             \
    __builtin_amdgcn_s_setprio(0);                                                \
  }

#define BAR   { __builtin_amdgcn_s_barrier(); __builtin_amdgcn_sched_barrier(0); }
#define VWAIT                                                                     \
  { if (BM == 256) { asm volatile("s_waitcnt vmcnt(4)" ::: "memory"); }           \
    else { asm volatile("s_waitcnt vmcnt(3)" ::: "memory"); } }
#define VW0   { asm volatile("s_waitcnt vmcnt(0)" ::: "memory"); }

  STA_(0, 0, 0); STB_(0, 0, 0); STB_(0, 1, 0); STA_(0, 1, 0);
  STA_(1, 0, 1); STB_(1, 1, 1);
  VWAIT;

  for (int T = 0; T < NT; T += 2) {
    const bool more = (T + 2) < NT;
    LDA_(0, 0); LDB_(0, 0);
    STB_(1, 0, T + 1);
    BAR; QMM(0, 0); BAR;
    LDB_(0, 1);
    STA_(1, 1, T + 1);
    BAR; QMM(0, 1); BAR;
    LDA_(0, 1);
    if (more) STA_(0, 0, T + 2);
    BAR; QMM(1, 1); BAR;
    if (more) { STB_(0, 1, T + 2); VWAIT; } else { VW0; }
    BAR; QMM(1, 0); BAR;
    LDA_(1, 0); LDB_(1, 0);
    if (more) STB_(0, 0, T + 2);
    BAR; QMM(0, 0); BAR;
    LDB_(1, 1);
    if (more) STA_(0, 1, T + 2);
    BAR; QMM(0, 1); BAR;
    LDA_(1, 1);
    if (more) STA_(1, 0, T + 3);
    BAR; QMM(1, 1); BAR;
    if (more) { STB_(1, 1, T + 3); VWAIT; }
    BAR; QMM(1, 0); BAR;
  }

  const int mat = bn >> 3;
  unsigned short* Cb = (unsigned short*)C;
  float* Cf = (float*)C;
#pragma unroll
  for (int mh = 0; mh < 2; ++mh)
#pragma unroll
    for (int mf = 0; mf < MF; ++mf)
#pragma unroll
      for (int j = 0; j < 4; ++j) {
        int row = m0 + mh * AH + wr * (AH / 2) + mf * 16 + kg * 4 + j;
        size_t rb = (size_t)mat * 8388608 + (size_t)row * 2048 + (size_t)((bn & 7) * 256);
#pragma unroll
        for (int bh = 0; bh < 2; ++bh)
#pragma unroll
          for (int nf = 0; nf < 2; ++nf) {
            int col = bh * 128 + wc * 32 + nf * 16 + ln;
            float v = acc[mh * MF + mf][bh * 2 + nf][j];
            if (OUT_F32) Cf[rb + col] = v;
            else Cb[rb + col] = f2b(v);
          }
      }
#undef STA_
#undef STB_
#undef LDA_
#undef LDB_
#undef QMM
#undef BAR
#undef VWAIT
#undef VW0
}

// ---------- flash attention (round-10 attn5 verbatim + setprio around MFMA clusters) ----------
__global__ __launch_bounds__(256, 2) void attn5_kernel(const unsigned short* __restrict__ Qb,
                                                       const unsigned short* __restrict__ Kb,
                                                       const unsigned short* __restrict__ Vt,
                                                       unsigned short* __restrict__ Ob) {
  __shared__ unsigned short KS[2][8192];
  __shared__ unsigned short VS[8192];
  __shared__ unsigned short PS[4][2048];
  const int D = 2048, L = 2048;
  int tid = threadIdx.x, lane = tid & 63, w = tid >> 6;
  int ln = lane & 15, kg = lane >> 4;
  int bid = blockIdx.x;
  int g = bid >> 5, bh = bid & 31;
  int qt = (g < 8) ? (15 - g) : (g - 8);
  int b = bh >> 4, h = bh & 15;
  const size_t base = (size_t)b * L * D + h * 128;
  const unsigned short* Kp = Kb + base;
  const unsigned short* Qp = Qb + base;
  unsigned short* Op = Ob + base;
  const unsigned short* Vp = Vt + (size_t)bh * 128 * L;

  int q0 = qt * 128;
  int qw0 = q0 + w * 32;

  bf16x8 aq[2][4];
#pragma unroll
  for (int m = 0; m < 2; ++m)
#pragma unroll
    for (int kc = 0; kc < 4; ++kc)
      aq[m][kc] = *(const bf16x8*)&Qp[(size_t)(qw0 + m * 16 + ln) * D + kc * 32 + kg * 8];

  f32x4 o[2][8] = {};
  float m2[2][4], ls[2][4];
#pragma unroll
  for (int m = 0; m < 2; ++m)
#pragma unroll
    for (int j = 0; j < 4; ++j) { m2[m][j] = -1e30f; ls[m][j] = 0.f; }

  int l16 = lane >> 4, l8 = lane >> 3, l7 = lane & 7;

#define STAGE_K(T, NB)                                                                 \
  { int kv0_ = (T) << 6;                                                               \
    _Pragma("unroll") for (int i = 0; i < 4; ++i) {                                    \
      int cK = w * 4 + i;                                                              \
      int r = cK * 4 + l16;                                                            \
      int sw = ln ^ (r & 7);                                                           \
      gl_lds16(Kp + (size_t)(kv0_ + r) * D + sw * 8, &KS[NB][cK * 512 + lane * 8]); } }
#define STAGE_V(T)                                                                     \
  { int kv0_ = (T) << 6;                                                               \
    _Pragma("unroll") for (int i = 0; i < 4; ++i) {                                    \
      int cK = w * 4 + i;                                                              \
      int dh = cK * 8 + l8;                                                            \
      int sv = l7 ^ (dh & 7);                                                          \
      gl_lds16(Vp + (size_t)dh * L + kv0_ + sv * 8, &VS[cK * 512 + lane * 8]); } }

  int nt = 2 * qt + 2;
  int mask_t = 2 * qt + (w >> 1);

  STAGE_K(0, 0);
  __syncthreads();

  for (int t = 0; t < nt; ++t) {
    int cur = t & 1;
    STAGE_V(t);
    bool morek = (t + 1) < nt;
    if (morek) STAGE_K(t + 1, cur ^ 1);

    if (t <= mask_t) {
      int kv0 = t << 6;
      f32x4 s[2][4] = {};
      __builtin_amdgcn_s_setprio(1);
#pragma unroll
      for (int n = 0; n < 4; ++n)
#pragma unroll
        for (int kc = 0; kc < 4; ++kc) {
          bf16x8 bk = *(const bf16x8*)&KS[cur][(n * 16 + ln) * 128 + (((kc << 2) + kg) ^ (ln & 7)) * 8];
          s[0][n] = __builtin_amdgcn_mfma_f32_16x16x32_bf16(aq[0][kc], bk, s[0][n], 0, 0, 0);
          s[1][n] = __builtin_amdgcn_mfma_f32_16x16x32_bf16(aq[1][kc], bk, s[1][n], 0, 0, 0);
        }
      __builtin_amdgcn_s_setprio(0);
      if (t == mask_t) {
#pragma unroll
        for (int m = 0; m < 2; ++m)
#pragma unroll
          for (int n = 0; n < 4; ++n)
#pragma unroll
            for (int j = 0; j < 4; ++j)
              if (kv0 + n * 16 + ln > qw0 + m * 16 + kg * 4 + j) s[m][n][j] = -1e30f;
      }
      float pmax[2][4];
      bool near = true;
#pragma unroll
      for (int m = 0; m < 2; ++m)
#pragma unroll
        for (int j = 0; j < 4; ++j) {
          pmax[m][j] = fmaxf(fmaxf(s[m][0][j], s[m][1][j]), fmaxf(s[m][2][j], s[m][3][j]));
          near = near && (pmax[m][j] <= m2[m][j] + 8.0f);
        }
      if (!__all(near)) {
#pragma unroll
        for (int m = 0; m < 2; ++m)
#pragma unroll
          for (int j = 0; j < 4; ++j) {
            float mx = pmax[m][j];
#pragma unroll
            for (int d = 1; d < 16; d <<= 1) mx = fmaxf(mx, __shfl_xor(mx, d));
            mx = fmaxf(mx, m2[m][j]);
            float al = __builtin_amdgcn_exp2f(m2[m][j] - mx);
            m2[m][j] = mx;
            ls[m][j] *= al;
#pragma unroll
            for (int dt = 0; dt < 8; ++dt) o[m][dt][j] *= al;
          }
      }
#pragma unroll
      for (int m = 0; m < 2; ++m)
#pragma unroll
        for (int j = 0; j < 4; ++j) {
          int row = m * 16 + kg * 4 + j;
          float acc = 0.f;
#pragma unroll
          for (int n = 0; n < 4; ++n) {
            float p = __builtin_amdgcn_exp2f(s[m][n][j] - m2[m][j]);
            acc += p;
            unsigned int u = __builtin_bit_cast(unsigned int, p);
            PS[w][row * 64 + (((n * 2 + (ln >> 3)) ^ (row & 7)) * 8) + (ln & 7)] =
                (unsigned short)(u >> 16);
          }
          ls[m][j] += acc;
        }
    }

    if (morek) { asm volatile("s_waitcnt vmcnt(4)" ::: "memory"); }
    else       { asm volatile("s_waitcnt vmcnt(0)" ::: "memory"); }
    __builtin_amdgcn_s_barrier();
    __builtin_amdgcn_sched_barrier(0);

    if (t <= mask_t) {
      __builtin_amdgcn_s_setprio(1);
#pragma unroll
      for (int kst = 0; kst < 2; ++kst) {
        bf16x8 ap0 = *(const bf16x8*)&PS[w][(ln) * 64 + (((kst << 2) + kg) ^ (ln & 7)) * 8];
        bf16x8 ap1 = *(const bf16x8*)&PS[w][(16 + ln) * 64 + (((kst << 2) + kg) ^ (ln & 7)) * 8];
#pragma unroll
        for (int dt = 0; dt < 8; ++dt) {
          bf16x8 bv = *(const bf16x8*)&VS[(dt * 16 + ln) * 64 + (((kst << 2) + kg) ^ (ln & 7)) * 8];
          o[0][dt] = __builtin_amdgcn_mfma_f32_16x16x32_bf16(ap0, bv, o[0][dt], 0, 0, 0);
          o[1][dt] = __builtin_amdgcn_mfma_f32_16x16x32_bf16(ap1, bv, o[1][dt], 0, 0, 0);
        }
      }
      __builtin_amdgcn_s_setprio(0);
    }
    __syncthreads();
  }
#undef STAGE_K
#undef STAGE_V

#pragma unroll
  for (int m = 0; m < 2; ++m)
#pragma unroll
    for (int j = 0; j < 4; ++j) {
      float tsum = ls[m][j];
#pragma unroll
      for (int d = 1; d < 16; d <<= 1) tsum += __shfl_xor(tsum, d);
      float inv = 1.0f / tsum;
      int row = qw0 + m * 16 + kg * 4 + j;
#pragma unroll
      for (int dt = 0; dt < 8; ++dt)
        Op[(size_t)row * D + dt * 16 + ln] = f2b(o[m][dt][j] * inv);
    }
}

// ---------- launch ----------
extern "C" void kernel_launch(void* const* d_in, const int* in_sizes, int n_in,
                              void* d_out, int out_size, void* d_ws, size_t ws_size,
                              hipStream_t stream) {
  const float* x  = (const float*)d_in[0];
  // d_in[1] = mask (causal; applied analytically)
  const float* Wq = (const float*)d_in[2];
  const float* Wk = (const float*)d_in[3];
  const float* Wv = (const float*)d_in[4];
  const float* Wo = (const float*)d_in[5];

  char* ws = (char*)d_ws;
  unsigned short* xb  = (unsigned short*)(ws + 0);
  unsigned short* wqb = (unsigned short*)(ws + 16777216);  // wq|wk|wv contiguous = [6144][2048]
  unsigned short* wkb = (unsigned short*)(ws + 25165824);
  unsigned short* wvb = (unsigned short*)(ws + 33554432);
  unsigned short* wob = (unsigned short*)(ws + 41943040);
  unsigned short* qb  = (unsigned short*)(ws + 50331648);  // q|k|v contiguous outputs
  unsigned short* kb  = (unsigned short*)(ws + 67108864);
  unsigned short* vb  = (unsigned short*)(ws + 83886080);
  float2* tab         = (float2*)(ws + 100663296);
  unsigned short* vt  = wqb;  // reuse wq+wk region after QKV GEMM
  unsigned short* ob  = xb;

  float* out  = (float*)d_out;
  float* kout = out + 8388608;
  float* vout = out + 16777216;

  // prep: casts + rope table (one launch)
  prep_kernel<<<dim3(8192, 6), 256, 0, stream>>>(x, xb, Wq, Wk, Wv, Wo, wqb, wkb, wvb, wob, tab);

  // fused QKV GEMM: BM=256 @ 384 blocks
  gemm4<256, 24, 0><<<384, 512, 0, stream>>>(xb, wqb, qb);

  // q-rope ∥ k-rope(+kout) ∥ v-transpose(+vout), one launch
  fix_kernel<<<dim3(16384, 3), 256, 0, stream>>>(qb, kb, kout, vb, vt, vout, tab);

  attn5_kernel<<<512, 256, 0, stream>>>(qb, kb, vt, ob);

  // output projection (fp32 out)
  gemm4<128, 8, 1><<<256, 512, 0, stream>>>(ob, wob, out);
}